// Round 2
// baseline (8703.934 us; speedup 1.0000x reference)
//
#include <hip/hip_runtime.h>
#include <hip/hip_bf16.h>
#include <cstddef>
#include <cstdint>

// ED_DCNN: deformable conv net, fp32 direct-conv baseline.
// Shapes (fixed by reference setup_inputs):
//   x: (4, 256, 8, 64, 64) fp32; images N=32 (= b*8+t), C1=256, H=W=64
//   w_off1: (512,256,3,3)  w1: (64,256,3,3)  bn1: 64
//   w_off2: (128,64,3,3)   w2: (64,64,3,3)   bn2: 64
//   out: (4, 64, 8, 64, 64) fp32

#define HWD 64
#define TS 16   // spatial tile edge
#define OCB 32  // output channels per block

// ---------------------------------------------------------------------------
// Direct 3x3 conv, stride 1, pad 1 (zero). One block: 16x16 spatial tile of
// one image, 32 output channels. Input staged in LDS (ICH channels/iter,
// 18x18 halo tile); weights via wave-uniform scalar loads.
// ---------------------------------------------------------------------------
template<int C, int ICH, bool BN, bool XPOSE_IN, bool XPOSE_OUT>
__global__ __launch_bounds__(256) void conv3x3_kernel(
    const float* __restrict__ in, const float* __restrict__ wgt,
    const float* __restrict__ g, const float* __restrict__ b,
    const float* __restrict__ m, const float* __restrict__ v,
    float* __restrict__ out, int Ochan)
{
    __shared__ float tile[ICH][18 * 18];

    const int n   = blockIdx.z;          // image 0..31
    const int ocb = blockIdx.y * OCB;    // output-channel slab base
    const int t4  = blockIdx.x;          // spatial tile 0..15
    const int ty0 = (t4 >> 2) * TS;
    const int tx0 = (t4 & 3) * TS;
    const int tid = threadIdx.x;
    const int tx  = tid & 15;
    const int ty  = tid >> 4;
    const int bb  = n >> 3;              // for XPOSE layouts (B,C,T,H,W)
    const int tt  = n & 7;

    float acc[OCB];
#pragma unroll
    for (int i = 0; i < OCB; ++i) acc[i] = 0.f;

    for (int ic0 = 0; ic0 < C; ic0 += ICH) {
        // ---- stage ICH channels of an 18x18 halo tile into LDS ----
        for (int idx = tid; idx < ICH * 18 * 18; idx += 256) {
            const int ch = idx / (18 * 18);
            const int r  = idx % (18 * 18);
            const int gy = ty0 + (r / 18) - 1;
            const int gx = tx0 + (r % 18) - 1;
            float val = 0.f;
            if (gy >= 0 && gy < HWD && gx >= 0 && gx < HWD) {
                const int ic = ic0 + ch;
                size_t src;
                if (XPOSE_IN)
                    src = ((((size_t)bb * C + ic) * 8 + tt) * HWD + gy) * HWD + gx;
                else
                    src = (((size_t)n * C + ic) * HWD + gy) * HWD + gx;
                val = in[src];
            }
            tile[ch][r] = val;
        }
        __syncthreads();

#pragma unroll
        for (int ch = 0; ch < ICH; ++ch) {
            float vv[9];
#pragma unroll
            for (int dy = 0; dy < 3; ++dy)
#pragma unroll
                for (int dx = 0; dx < 3; ++dx)
                    vv[dy * 3 + dx] = tile[ch][(ty + dy) * 18 + (tx + dx)];

            const float* wp = &wgt[((size_t)ocb * C + (ic0 + ch)) * 9];
#pragma unroll
            for (int oc = 0; oc < OCB; ++oc) {
                const float* w9 = wp + (size_t)oc * C * 9;  // wave-uniform -> s_load
#pragma unroll
                for (int k = 0; k < 9; ++k)
                    acc[oc] = fmaf(vv[k], w9[k], acc[oc]);
            }
        }
        __syncthreads();
    }

    const int oy = ty0 + ty, ox = tx0 + tx;
#pragma unroll
    for (int oc = 0; oc < OCB; ++oc) {
        float y = acc[oc];
        const int o = ocb + oc;
        if constexpr (BN) {
            const float scale = g[o] / sqrtf(v[o] + 1e-5f);
            y = (y - m[o]) * scale + b[o];
            y = y > 0.f ? y : 0.01f * y;
        }
        size_t dst;
        if (XPOSE_OUT)
            dst = ((((size_t)bb * Ochan + o) * 8 + tt) * HWD + oy) * HWD + ox;
        else
            dst = (((size_t)n * Ochan + o) * HWD + oy) * HWD + ox;
        out[dst] = y;
    }
}

// ---------------------------------------------------------------------------
// Deformable bilinear sampler. One thread per (p = n*C+c, h, w) point.
// off is the flat (N, 2C, H, W) conv output; the reference's view means
// dy = off[(p*HW + h*W + w)*2], dx = off[... + 1].
// ---------------------------------------------------------------------------
template<int C, bool XPOSE_IN>
__global__ __launch_bounds__(256) void deform_sample_kernel(
    const float* __restrict__ src, const float* __restrict__ off,
    float* __restrict__ out, int total)
{
    const int i = blockIdx.x * blockDim.x + threadIdx.x;
    if (i >= total) return;

    const int w = i & 63;
    const int h = (i >> 6) & 63;
    const int p = i >> 12;          // n*C + c

    const float dy = off[(size_t)i * 2];
    const float dx = off[(size_t)i * 2 + 1];

    float cy = fminf(fmaxf((float)h + dy, 0.f), 63.f);
    float cx = fminf(fmaxf((float)w + dx, 0.f), 63.f);
    const float y0f = floorf(cy), x0f = floorf(cx);
    const float fy = cy - y0f, fx = cx - x0f;
    const int y0 = (int)y0f, x0 = (int)x0f;
    const int y1 = min(y0 + 1, 63), x1 = min(x0 + 1, 63);

    const float* mp;
    if (XPOSE_IN) {
        const int c = p & (C - 1);
        const int n = p / C;
        const int bb = n >> 3, tt = n & 7;
        mp = src + ((((size_t)bb * C + c) * 8 + tt) << 12);
    } else {
        mp = src + ((size_t)p << 12);
    }
    const float v00 = mp[(y0 << 6) + x0];
    const float v01 = mp[(y0 << 6) + x1];
    const float v10 = mp[(y1 << 6) + x0];
    const float v11 = mp[(y1 << 6) + x1];

    out[i] = v00 * (1.f - fy) * (1.f - fx) + v01 * (1.f - fy) * fx +
             v10 * fy * (1.f - fx) + v11 * fy * fx;
}

// ---------------------------------------------------------------------------
extern "C" void kernel_launch(void* const* d_in, const int* in_sizes, int n_in,
                              void* d_out, int out_size, void* d_ws, size_t ws_size,
                              hipStream_t stream) {
    const float* x      = (const float*)d_in[0];
    const float* w_off1 = (const float*)d_in[3];
    const float* w1     = (const float*)d_in[4];
    const float* g1     = (const float*)d_in[5];
    const float* b1     = (const float*)d_in[6];
    const float* m1     = (const float*)d_in[7];
    const float* v1     = (const float*)d_in[8];
    const float* w_off2 = (const float*)d_in[9];
    const float* w2     = (const float*)d_in[10];
    const float* g2     = (const float*)d_in[11];
    const float* b2     = (const float*)d_in[12];
    const float* m2     = (const float*)d_in[13];
    const float* v2     = (const float*)d_in[14];
    float* out = (float*)d_out;

    char* ws = (char*)d_ws;
    // Scratch layout (regions reused once producers/consumers are done):
    //   off1:   [0, 256MB)           32*512*4096 f32
    //   samp1:  [256MB, 384MB)       32*256*4096 f32
    //   h1:     [0, 32MB)            32*64*4096 f32   (off1 dead)
    //   off2:   [32MB, 96MB)         32*128*4096 f32
    //   samp2:  [96MB, 128MB)        32*64*4096 f32
    float* off1  = (float*)(ws);
    float* samp1 = (float*)(ws + (size_t)268435456);
    float* h1    = (float*)(ws);
    float* off2  = (float*)(ws + (size_t)33554432);
    float* samp2 = (float*)(ws + (size_t)100663296);

    // stage 1
    conv3x3_kernel<256, 2, false, true, false>
        <<<dim3(16, 512 / OCB, 32), 256, 0, stream>>>(
            x, w_off1, nullptr, nullptr, nullptr, nullptr, off1, 512);

    deform_sample_kernel<256, true>
        <<<(32 * 256 * 4096) / 256, 256, 0, stream>>>(x, off1, samp1, 32 * 256 * 4096);

    conv3x3_kernel<256, 2, true, false, false>
        <<<dim3(16, 64 / OCB, 32), 256, 0, stream>>>(
            samp1, w1, g1, b1, m1, v1, h1, 64);

    // stage 2
    conv3x3_kernel<64, 2, false, false, false>
        <<<dim3(16, 128 / OCB, 32), 256, 0, stream>>>(
            h1, w_off2, nullptr, nullptr, nullptr, nullptr, off2, 128);

    deform_sample_kernel<64, false>
        <<<(32 * 64 * 4096) / 256, 256, 0, stream>>>(h1, off2, samp2, 32 * 64 * 4096);

    conv3x3_kernel<64, 2, true, false, true>
        <<<dim3(16, 64 / OCB, 32), 256, 0, stream>>>(
            samp2, w2, g2, b2, m2, v2, out, 64);
}

// Round 4
// 1152.470 us; speedup vs baseline: 7.5524x; 7.5524x over previous
//
#include <hip/hip_runtime.h>
#include <hip/hip_bf16.h>
#include <cstddef>
#include <cstdint>

// ED_DCNN — bf16 MFMA implicit-GEMM rewrite.
// Convs: tap-decomposed implicit GEMM, D[pos][oc] = sum_tap sum_c A[pos][c]*W[tap][c][oc]
//   block: BM=128 positions (4x32 spatial patch) x BN=64 oc; 256 thr = 4 waves (2Mx2N)
//   wave tile 64M x 32N via mfma_f32_16x16x32_bf16 (frags: A row=lane&15, k=(lane>>4)*8+j;
//   B col=lane&15 same k; D col=lane&15, row=(lane>>4)*4+reg  [m89-verified])
// LDS: A halo tile [204 spatial][32 c] bf16, XOR-swizzled granules (g^= (s>>1)&3) for
//   conflict-free ds_read_b128; B slice [9 tap][64 o][32 c] pre-swizzled in global wt.

using short8 = __attribute__((ext_vector_type(8))) short;
using f32x4  = __attribute__((ext_vector_type(4))) float;

__device__ __forceinline__ unsigned short f2bf(float f) {
    unsigned int u = __float_as_uint(f);
    return (unsigned short)((u + 0x7fffu + ((u >> 16) & 1u)) >> 16);  // RNE
}
__device__ __forceinline__ float bf2f(unsigned short u) {
    return __uint_as_float(((unsigned int)u) << 16);
}

// IN_MODE: 1 = fp32 x in (B,C,8,64,64) layout (n=b*8+t); 0 = bf16 (N,C,64,64)
// OUT_MODE: 0 = bf16 (N,O,64,64); 1 = fp32 (B,O,8,64,64)
template<int C, int O, int IN_MODE, bool BN_ACT, int OUT_MODE>
__global__ __launch_bounds__(256) void conv_mfma(
    const void* __restrict__ inv, const unsigned short* __restrict__ wt,
    const float* __restrict__ gg, const float* __restrict__ bb,
    const float* __restrict__ mmn, const float* __restrict__ vvr,
    void* __restrict__ outv)
{
    constexpr int SLICES = C / 32;
    __shared__ __align__(16) char smem[204*64 + 9*64*64];  // A 13056 + B 36864 = 49920
    char* aL = smem;
    char* bL = smem + 204*64;

    const int nb  = blockIdx.x;          // N-block (oc slab)
    const int mb  = blockIdx.y;          // M-block
    const int n   = mb >> 5;             // image 0..31
    const int til = mb & 31;
    const int ty0 = (til >> 1) << 2;     // 4-row patch
    const int tx0 = (til & 1) << 5;      // 32-col patch
    const int o0  = nb << 6;
    const int tid = threadIdx.x;
    const int lane = tid & 63;
    const int wave = tid >> 6;
    const int wm = wave >> 1, wn = wave & 1;
    const int l15 = lane & 15, cblk = lane >> 4;

    // A-fragment spatial bases (halo coords: s = (py+ky)*34 + (px+kx))
    int s0[4];
#pragma unroll
    for (int mf = 0; mf < 4; ++mf) {
        const int Ml = wm*64 + mf*16 + l15;
        s0[mf] = (Ml >> 5) * 34 + (Ml & 31);
    }
    // B-fragment LDS offsets (within tap block)
    int boff[2];
#pragma unroll
    for (int nf = 0; nf < 2; ++nf) {
        const int o = wn*32 + nf*16 + l15;
        boff[nf] = (o << 6) + ((((o >> 1) ^ cblk) & 3) << 4);
    }

    f32x4 acc[4][2];
#pragma unroll
    for (int i = 0; i < 4; ++i)
#pragma unroll
        for (int j = 0; j < 2; ++j) acc[i][j] = f32x4{0.f, 0.f, 0.f, 0.f};

    const int sx = tid & 31;   // staging: main-region column
    const int c8 = tid >> 5;   // staging: within-granule channel 0..7

    for (int sl = 0; sl < SLICES; ++sl) {
        const int ic0 = sl << 5;
        __syncthreads();
        // ---- stage A: main 6x32 region (coalesced rows) ----
#pragma unroll
        for (int ci = 0; ci < 4; ++ci) {
            const int c = ic0 + ci*8 + c8;
            size_t chbase;
            if constexpr (IN_MODE == 1)
                chbase = (size_t)((((n >> 3)*C + c)*8 + (n & 7))) << 12;
            else
                chbase = ((size_t)n*C + c) << 12;
#pragma unroll
            for (int ry = 0; ry < 6; ++ry) {
                const int gy = ty0 - 1 + ry;
                float val = 0.f;
                if ((unsigned)gy < 64u) {
                    const size_t gidx = chbase + (gy << 6) + (tx0 + sx);
                    if constexpr (IN_MODE == 1) val = ((const float*)inv)[gidx];
                    else val = bf2f(((const unsigned short*)inv)[gidx]);
                }
                const int s = ry*34 + sx + 1;
                const int ad = (s << 6) + ((((s >> 1) ^ ci) & 3) << 4) + (c8 << 1);
                *(unsigned short*)(aL + ad) = f2bf(val);
            }
        }
        // ---- stage A: halo columns gx = tx0-1, tx0+32 ----
        if (tid < 192) {
            const int cl = tid & 31;
            const int ry = tid >> 5;   // 0..5
            const int gy = ty0 - 1 + ry;
            const int c  = ic0 + cl;
            const int ci = cl >> 3, cw = cl & 7;
            size_t chbase;
            if constexpr (IN_MODE == 1)
                chbase = (size_t)((((n >> 3)*C + c)*8 + (n & 7))) << 12;
            else
                chbase = ((size_t)n*C + c) << 12;
#pragma unroll
            for (int side = 0; side < 2; ++side) {
                const int gx = side ? (tx0 + 32) : (tx0 - 1);
                float val = 0.f;
                if ((unsigned)gy < 64u && (unsigned)gx < 64u) {
                    const size_t gidx = chbase + (gy << 6) + gx;
                    if constexpr (IN_MODE == 1) val = ((const float*)inv)[gidx];
                    else val = bf2f(((const unsigned short*)inv)[gidx]);
                }
                const int s = ry*34 + (side ? 33 : 0);
                const int ad = (s << 6) + ((((s >> 1) ^ ci) & 3) << 4) + (cw << 1);
                *(unsigned short*)(aL + ad) = f2bf(val);
            }
        }
        // ---- stage B: contiguous copy of pre-swizzled weight slice ----
        {
            const size_t sbase = ((size_t)sl*9*O + o0) * 32;  // ushort elems
#pragma unroll
            for (int i = 0; i < 9; ++i) {
                const int chunk = tid + (i << 8);   // 0..2303
                const int tap = chunk >> 8;
                const int q   = chunk & 255;
                short8 d = *(const short8*)(wt + sbase + (size_t)tap*O*32 + (q << 3));
                *(short8*)(bL + (chunk << 4)) = d;
            }
        }
        __syncthreads();
        // ---- compute: 9 taps x (4 mf x 2 nf) MFMA ----
#pragma unroll
        for (int tap = 0; tap < 9; ++tap) {
            const int D = (tap/3)*34 + (tap%3);
            short8 bf0 = *(const short8*)(bL + tap*4096 + boff[0]);
            short8 bf1 = *(const short8*)(bL + tap*4096 + boff[1]);
#pragma unroll
            for (int mf = 0; mf < 4; ++mf) {
                const int s = s0[mf] + D;
                const int ad = (s << 6) + ((((s >> 1) ^ cblk) & 3) << 4);
                short8 af = *(const short8*)(aL + ad);
                acc[mf][0] = __builtin_amdgcn_mfma_f32_16x16x32_bf16(af, bf0, acc[mf][0], 0, 0, 0);
                acc[mf][1] = __builtin_amdgcn_mfma_f32_16x16x32_bf16(af, bf1, acc[mf][1], 0, 0, 0);
            }
        }
    }

    // ---- epilogue: LDS transpose, fused BN+LeakyReLU, coalesced stores ----
    __syncthreads();
    float* eL = (float*)smem;   // [64 oc][132] (pad vs 128 to break bank stride)
#pragma unroll
    for (int nf = 0; nf < 2; ++nf) {
        const int oc = wn*32 + nf*16 + l15;
#pragma unroll
        for (int mf = 0; mf < 4; ++mf) {
#pragma unroll
            for (int r = 0; r < 4; ++r) {
                const int Ml = wm*64 + mf*16 + ((lane >> 4) << 2) + r;
                eL[oc*132 + Ml] = acc[mf][nf][r];
            }
        }
    }
    __syncthreads();
#pragma unroll
    for (int i = 0; i < 16; ++i) {
        const int idx = (tid + (i << 8)) << 1;   // 2 consecutive Ml per thread
        const int oc = idx >> 7;
        const int Ml = idx & 127;
        float v0 = eL[oc*132 + Ml];
        float v1 = eL[oc*132 + Ml + 1];
        const int o = o0 + oc;
        if constexpr (BN_ACT) {
            const float sc = gg[o] * __frsqrt_rn(vvr[o] + 1e-5f);
            const float sh = bb[o] - mmn[o]*sc;
            v0 = v0*sc + sh; v1 = v1*sc + sh;
            v0 = v0 > 0.f ? v0 : 0.01f*v0;
            v1 = v1 > 0.f ? v1 : 0.01f*v1;
        }
        const int y = ty0 + (Ml >> 5);
        const int x = tx0 + (Ml & 31);
        if constexpr (OUT_MODE == 0) {
            const size_t e = (((size_t)n*O + o) << 12) + (y << 6) + x;
            const unsigned int pk = (unsigned int)f2bf(v0) | ((unsigned int)f2bf(v1) << 16);
            *(unsigned int*)((unsigned short*)outv + e) = pk;
        } else {
            size_t e = (size_t)(((n >> 3)*O + o)*8 + (n & 7));
            e = (e << 12) + (y << 6) + x;
            *(float2*)((float*)outv + e) = make_float2(v0, v1);
        }
    }
}

// ---------------------------------------------------------------------------
// Weight transpose + pre-swizzle: w(O,C,3,3) fp32 -> wt[slice][tap][o][granule][8] bf16
// granule position gq holds channels c = slice*32 + ((gq ^ (o>>1))&3)*8 + j
// ---------------------------------------------------------------------------
__global__ __launch_bounds__(256) void wt_xpose(
    const float* __restrict__ w, unsigned short* __restrict__ wt,
    int C, int O, int total)
{
    const int idx = blockIdx.x*256 + threadIdx.x;
    if (idx >= total) return;
    const int j   = idx & 7;
    const int gq  = (idx >> 3) & 3;
    const int o   = (idx >> 5) % O;
    const int st  = idx / (O * 32);
    const int tap = st % 9;
    const int s   = st / 9;
    const int c   = (s << 5) + (((gq ^ (o >> 1)) & 3) << 3) + j;
    wt[idx] = f2bf(w[((size_t)o*C + c)*9 + tap]);
}

// ---------------------------------------------------------------------------
// Deformable bilinear sampler, 2 horizontal points/thread.
// off is bf16 flat (N,2C,H,W) viewed as (N*C,H,W,2): dy=off[i*2], dx=off[i*2+1].
// IN_MODE 1: src = fp32 x in (B,C,8,64,64); 0: src bf16 (N,C,64,64). Out bf16.
// ---------------------------------------------------------------------------
template<int C, int IN_MODE>
__global__ __launch_bounds__(256) void deform2(
    const void* __restrict__ srcv, const unsigned short* __restrict__ off,
    unsigned short* __restrict__ outp, int total2)
{
    const int gid = blockIdx.x*256 + threadIdx.x;
    if (gid >= total2) return;
    const int i0 = gid << 1;
    const int p  = i0 >> 12;           // n*C + c
    const int h  = (i0 >> 6) & 63;
    const int w0 = i0 & 63;
    constexpr int LOGC = (C == 256) ? 8 : 6;

    const uint2 ob = *(const uint2*)(off + ((size_t)i0 << 1));  // dy0,dx0,dy1,dx1
    const float dys[2] = { bf2f((unsigned short)(ob.x & 0xffff)),
                           bf2f((unsigned short)(ob.y & 0xffff)) };
    const float dxs[2] = { bf2f((unsigned short)(ob.x >> 16)),
                           bf2f((unsigned short)(ob.y >> 16)) };

    const float* qf = nullptr; const unsigned short* qh = nullptr;
    if constexpr (IN_MODE == 1) {
        const int c = p & (C - 1);
        const int nn = p >> LOGC;
        qf = (const float*)srcv + ((size_t)((((nn >> 3)*C + c)*8 + (nn & 7))) << 12);
    } else {
        qh = (const unsigned short*)srcv + ((size_t)p << 12);
    }

    float r[2];
#pragma unroll
    for (int k = 0; k < 2; ++k) {
        const float cy = fminf(fmaxf((float)h + dys[k], 0.f), 63.f);
        const float cx = fminf(fmaxf((float)(w0 + k) + dxs[k], 0.f), 63.f);
        const float y0f = floorf(cy), x0f = floorf(cx);
        const float fy = cy - y0f, fx = cx - x0f;
        const int y0 = (int)y0f, x0 = (int)x0f;
        const int y1 = min(y0 + 1, 63), x1 = min(x0 + 1, 63);
        float v00, v01, v10, v11;
        if constexpr (IN_MODE == 1) {
            v00 = qf[(y0 << 6) + x0]; v01 = qf[(y0 << 6) + x1];
            v10 = qf[(y1 << 6) + x0]; v11 = qf[(y1 << 6) + x1];
        } else {
            v00 = bf2f(qh[(y0 << 6) + x0]); v01 = bf2f(qh[(y0 << 6) + x1]);
            v10 = bf2f(qh[(y1 << 6) + x0]); v11 = bf2f(qh[(y1 << 6) + x1]);
        }
        r[k] = v00*(1.f-fy)*(1.f-fx) + v01*(1.f-fy)*fx + v10*fy*(1.f-fx) + v11*fy*fx;
    }
    const unsigned int pk = (unsigned int)f2bf(r[0]) | ((unsigned int)f2bf(r[1]) << 16);
    *(unsigned int*)(outp + i0) = pk;
}

// ---------------------------------------------------------------------------
extern "C" void kernel_launch(void* const* d_in, const int* in_sizes, int n_in,
                              void* d_out, int out_size, void* d_ws, size_t ws_size,
                              hipStream_t stream) {
    const float* x      = (const float*)d_in[0];
    const float* w_off1 = (const float*)d_in[3];
    const float* w1     = (const float*)d_in[4];
    const float* g1     = (const float*)d_in[5];
    const float* b1     = (const float*)d_in[6];
    const float* m1     = (const float*)d_in[7];
    const float* v1     = (const float*)d_in[8];
    const float* w_off2 = (const float*)d_in[9];
    const float* w2     = (const float*)d_in[10];
    const float* g2     = (const float*)d_in[11];
    const float* m2     = (const float*)d_in[13];
    const float* b2     = (const float*)d_in[12];
    const float* v2     = (const float*)d_in[14];
    float* out = (float*)d_out;

    char* ws = (char*)d_ws;
    // ws layout (bytes):
    //   wt1    @ 0        (2,359,296)   wth1 @ 4MB (294,912)
    //   wtoff2 @ 8MB      (147,456)     wth2 @ 12MB (73,728)
    //   off1   @ 16MB     (134,217,728 bf16)
    //   samp1  @ 150,994,944 (67,108,864)
    //   h1     @ 218,103,808 (16,777,216)
    //   off2   @ 234,881,024 (33,554,432)
    //   samp2  @ 268,435,456 (16,777,216)   end = 285,212,672 (~272MB)
    unsigned short* wt1    = (unsigned short*)(ws);
    unsigned short* wth1   = (unsigned short*)(ws + (4u << 20));
    unsigned short* wtoff2 = (unsigned short*)(ws + (8u << 20));
    unsigned short* wth2   = (unsigned short*)(ws + (12u << 20));
    unsigned short* off1   = (unsigned short*)(ws + (16u << 20));
    unsigned short* samp1  = (unsigned short*)(ws + 150994944ull);
    unsigned short* h1     = (unsigned short*)(ws + 218103808ull);
    unsigned short* off2   = (unsigned short*)(ws + 234881024ull);
    unsigned short* samp2  = (unsigned short*)(ws + 268435456ull);

    // weight transposes (tiny)
    wt_xpose<<<4608, 256, 0, stream>>>(w_off1, wt1,    256, 512, 1179648);
    wt_xpose<<<576,  256, 0, stream>>>(w1,     wth1,   256, 64,  147456);
    wt_xpose<<<288,  256, 0, stream>>>(w_off2, wtoff2, 64,  128, 73728);
    wt_xpose<<<144,  256, 0, stream>>>(w2,     wth2,   64,  64,  36864);

    // stage 1
    conv_mfma<256, 512, 1, false, 0><<<dim3(8, 1024), 256, 0, stream>>>(
        x, wt1, nullptr, nullptr, nullptr, nullptr, off1);
    deform2<256, 1><<<65536, 256, 0, stream>>>(x, off1, samp1, 16777216);
    conv_mfma<256, 64, 0, true, 0><<<dim3(1, 1024), 256, 0, stream>>>(
        samp1, wth1, g1, b1, m1, v1, h1);

    // stage 2
    conv_mfma<64, 128, 0, false, 0><<<dim3(2, 1024), 256, 0, stream>>>(
        h1, wtoff2, nullptr, nullptr, nullptr, nullptr, off2);
    deform2<64, 0><<<16384, 256, 0, stream>>>(h1, off2, samp2, 4194304);
    conv_mfma<64, 64, 0, true, 1><<<dim3(1, 1024), 256, 0, stream>>>(
        samp2, wth2, g2, b2, m2, v2, out);
}

// Round 6
// 776.458 us; speedup vs baseline: 11.2098x; 1.4843x over previous
//
#include <hip/hip_runtime.h>
#include <hip/hip_bf16.h>
#include <cstddef>
#include <cstdint>

// ED_DCNN v3 — NHWC bf16 implicit-GEMM with global_load_lds DMA staging.
// conv: D[pos][oc] = sum_tap sum_c A[pos][c] * W[tap][c][oc]
//   BM positions x BN=64 oc per block, 4 waves, wave tile (BM/4)x64
//   mfma_f32_16x16x32_bf16; A granule-swizzled via SOURCE permutation
//   (LDS linear for global_load_lds), B pre-swizzled in global.

using short8 = __attribute__((ext_vector_type(8))) short;
using f32x4  = __attribute__((ext_vector_type(4))) float;

__device__ __forceinline__ unsigned short f2bf(float f) {
    unsigned int u = __float_as_uint(f);
    return (unsigned short)((u + 0x7fffu + ((u >> 16) & 1u)) >> 16);  // RNE
}
__device__ __forceinline__ float bf2f(unsigned short u) {
    return __uint_as_float(((unsigned int)u) << 16);
}
__device__ __forceinline__ void gload16(const void* g, void* l) {
    __builtin_amdgcn_global_load_lds(
        (const __attribute__((address_space(1))) void*)g,
        (__attribute__((address_space(3))) void*)l, 16, 0, 0);
}

// ---------------------------------------------------------------------------
// conv3x3 implicit GEMM.  in: NHWC bf16 [32][64][64][C].  out per OUT_MODE:
//   0: bf16 NCHW (N,O,64,64)   1: fp32 (B,O,8,64,64)
// wt: pre-swizzled [C/32 slice][9 tap][O][4 gq][8c] bf16 (gq holds channels
//   ((gq^(o>>1))&3)*8..+7 of the slice).
// ---------------------------------------------------------------------------
template<int C, int O, int BM, bool BN_ACT, int OUT_MODE>
__global__ __launch_bounds__(256, 2) void conv_mfma(
    const unsigned short* __restrict__ in, const unsigned short* __restrict__ wt,
    const unsigned short* __restrict__ zp,
    const float* __restrict__ gg, const float* __restrict__ bbv,
    const float* __restrict__ mmn, const float* __restrict__ vvr,
    void* __restrict__ outv)
{
    constexpr int ROWS = BM / 32;            // spatial rows per tile
    constexpr int S    = (ROWS + 2) * 34;    // halo positions
    constexpr int AGR  = S * 4;              // A granules (16B each)
    constexpr int ABYTES = S * 64;
    constexpr int WM   = BM / 4;             // wave M tile
    constexpr int MF   = WM / 16;
    constexpr int NX   = O / 64;
    constexpr int NMB  = 131072 / BM;        // M blocks
    constexpr int CHUNK = NMB / 8;
    constexpr int TPI  = NMB / 32;           // tiles per image
    constexpr int SLICES = C / 32;

    __shared__ __align__(16) char smem[ABYTES + 36864];
    char* aL = smem;
    char* bL = smem + ABYTES;

    // bijective XCD-chunk swizzle: XCD owns an M-chunk for ALL N-slabs;
    // blocks sharing an A tile (same mb, all nsl) land on the same XCD.
    const int d   = blockIdx.y * NX + blockIdx.x;
    const int xcd = d & 7;
    const int j   = d >> 3;
    const int mb  = xcd * CHUNK + j / NX;
    const int nsl = j % NX;

    const int n   = mb / TPI;
    const int til = mb % TPI;
    const int ty0 = (til >> 1) * ROWS;
    const int tx0 = (til & 1) << 5;
    const int o0  = nsl << 6;

    const int tid  = threadIdx.x;
    const int lane = tid & 63;
    const int wave = tid >> 6;
    const int l15  = lane & 15, cblk = lane >> 4;

    int s0[MF];
#pragma unroll
    for (int mf = 0; mf < MF; ++mf) {
        const int Ml = wave * WM + mf * 16 + l15;
        s0[mf] = (Ml >> 5) * 34 + (Ml & 31);
    }
    int boff[4];
#pragma unroll
    for (int nf = 0; nf < 4; ++nf) {
        const int o = nf * 16 + l15;
        boff[nf] = (o << 6) + ((((o >> 1) ^ cblk) & 3) << 4);
    }

    f32x4 acc[MF][4];
#pragma unroll
    for (int i = 0; i < MF; ++i)
#pragma unroll
        for (int k = 0; k < 4; ++k) acc[i][k] = f32x4{0.f, 0.f, 0.f, 0.f};

    for (int sl = 0; sl < SLICES; ++sl) {
        const int ic0 = sl << 5;
        __syncthreads();   // protect LDS reads of previous slice
        // ---- A stage: DMA, source-permuted granules, LDS linear ----
        constexpr int AIT = (AGR + 255) / 256;
#pragma unroll
        for (int it = 0; it < AIT; ++it) {
            const int gi = it * 256 + tid;
            if (gi < AGR) {
                const int s  = gi >> 2;
                const int gp = gi & 3;
                const int gl = gp ^ ((s >> 1) & 3);
                const int r  = s / 34, cc = s % 34;
                const int gy = ty0 - 1 + r, gx = tx0 - 1 + cc;
                const unsigned short* src;
                if ((unsigned)gy < 64u && (unsigned)gx < 64u)
                    src = in + ((size_t)((n << 12) + (gy << 6) + gx)) * C + ic0 + (gl << 3);
                else
                    src = zp + ((gi & 255) << 3);
                gload16(src, aL + (gi << 4));
            }
        }
        // ---- B stage: DMA, contiguous pre-swizzled ----
        {
            const unsigned short* wsl = wt + (size_t)sl * (9 * O * 32) + (size_t)o0 * 32;
#pragma unroll
            for (int it = 0; it < 9; ++it) {
                const int gi  = it * 256 + tid;
                const int tap = gi >> 8;
                const int q   = gi & 255;
                gload16(wsl + (size_t)tap * O * 32 + (q << 3), bL + (gi << 4));
            }
        }
        asm volatile("s_waitcnt vmcnt(0)" ::: "memory");
        __syncthreads();
        // ---- compute ----
#pragma unroll
        for (int tap = 0; tap < 9; ++tap) {
            const int D = (tap / 3) * 34 + (tap % 3);
            short8 bfr[4];
#pragma unroll
            for (int nf = 0; nf < 4; ++nf)
                bfr[nf] = *(const short8*)(bL + tap * 4096 + boff[nf]);
#pragma unroll
            for (int mf = 0; mf < MF; ++mf) {
                const int s  = s0[mf] + D;
                const int ad = (s << 6) + ((((s >> 1) ^ cblk) & 3) << 4);
                short8 af = *(const short8*)(aL + ad);
#pragma unroll
                for (int nf = 0; nf < 4; ++nf)
                    acc[mf][nf] = __builtin_amdgcn_mfma_f32_16x16x32_bf16(
                        af, bfr[nf], acc[mf][nf], 0, 0, 0);
            }
        }
    }

    // ---- epilogue: direct stores (4 consecutive x per thread) ----
    float sc[4], sh[4];
    if constexpr (BN_ACT) {
#pragma unroll
        for (int nf = 0; nf < 4; ++nf) {
            const int o = o0 + nf * 16 + l15;
            sc[nf] = gg[o] * __frsqrt_rn(vvr[o] + 1e-5f);
            sh[nf] = bbv[o] - mmn[o] * sc[nf];
        }
    }
    const int q = lane >> 4;
#pragma unroll
    for (int mf = 0; mf < MF; ++mf) {
        const int Mp  = wave * WM + mf * 16 + q * 4;
        const int gy  = ty0 + (Mp >> 5);
        const int gx  = tx0 + (Mp & 31);
#pragma unroll
        for (int nf = 0; nf < 4; ++nf) {
            const int o = o0 + nf * 16 + l15;
            float y0 = acc[mf][nf][0], y1 = acc[mf][nf][1];
            float y2 = acc[mf][nf][2], y3 = acc[mf][nf][3];
            if constexpr (BN_ACT) {
                y0 = y0 * sc[nf] + sh[nf]; y0 = y0 > 0.f ? y0 : 0.01f * y0;
                y1 = y1 * sc[nf] + sh[nf]; y1 = y1 > 0.f ? y1 : 0.01f * y1;
                y2 = y2 * sc[nf] + sh[nf]; y2 = y2 > 0.f ? y2 : 0.01f * y2;
                y3 = y3 * sc[nf] + sh[nf]; y3 = y3 > 0.f ? y3 : 0.01f * y3;
            }
            if constexpr (OUT_MODE == 0) {
                const size_t e = (((size_t)n * O + o) << 12) + (gy << 6) + gx;
                uint2 pk;
                pk.x = (unsigned)f2bf(y0) | ((unsigned)f2bf(y1) << 16);
                pk.y = (unsigned)f2bf(y2) | ((unsigned)f2bf(y3) << 16);
                *(uint2*)((unsigned short*)outv + e) = pk;
            } else {
                size_t e = (size_t)(((n >> 3) * O + o) * 8 + (n & 7));
                e = (e << 12) + (gy << 6) + gx;
                *(float4*)((float*)outv + e) = make_float4(y0, y1, y2, y3);
            }
        }
    }
}

// ---------------------------------------------------------------------------
// Weight transpose + pre-swizzle (unchanged, proven r2).
// ---------------------------------------------------------------------------
__global__ __launch_bounds__(256) void wt_xpose(
    const float* __restrict__ w, unsigned short* __restrict__ wt,
    int C, int O, int total)
{
    const int idx = blockIdx.x * 256 + threadIdx.x;
    if (idx >= total) return;
    const int j   = idx & 7;
    const int gq  = (idx >> 3) & 3;
    const int o   = (idx >> 5) % O;
    const int st  = idx / (O * 32);
    const int tap = st % 9;
    const int s   = st / 9;
    const int c   = (s << 5) + (((gq ^ (o >> 1)) & 3) << 3) + j;
    wt[idx] = f2bf(w[((size_t)o * C + c) * 9 + tap]);
}

// ---------------------------------------------------------------------------
// x (4,256,8,64,64) fp32 -> xh NHWC bf16 [n][y][x][256]
// ---------------------------------------------------------------------------
__global__ __launch_bounds__(256) void xpose_in(
    const float* __restrict__ x, unsigned short* __restrict__ xh)
{
    __shared__ unsigned short sm[256][66];
    const int y = blockIdx.x, n = blockIdx.y;
    const int tid = threadIdx.x;
    const int bb = n >> 3, tt = n & 7;
#pragma unroll
    for (int i = 0; i < 64; ++i) {
        const int idx = (i << 8) + tid;
        const int xx = idx & 63, c = idx >> 6;
        const float v = x[(((size_t)((bb << 8) + c) * 8 + tt) << 12) + (y << 6) + xx];
        sm[c][xx] = f2bf(v);
    }
    __syncthreads();
    const size_t ob = (((size_t)(n << 12)) + (y << 6)) << 8;   // *256
#pragma unroll
    for (int xx = 0; xx < 64; ++xx)
        xh[ob + ((size_t)xx << 8) + tid] = sm[tid][xx];
}

// ---------------------------------------------------------------------------
// h1 NCHW bf16 (32,64,64,64) -> NHWC bf16
// ---------------------------------------------------------------------------
__global__ __launch_bounds__(256) void xpose64(
    const unsigned short* __restrict__ src, unsigned short* __restrict__ dst)
{
    __shared__ unsigned short sm[64][66];
    const int y = blockIdx.x, n = blockIdx.y;
    const int tid = threadIdx.x;
#pragma unroll
    for (int i = 0; i < 16; ++i) {
        const int idx = (i << 8) + tid;
        const int xx = idx & 63, c = idx >> 6;
        sm[c][xx] = src[(((size_t)(n << 6) + c) << 12) + (y << 6) + xx];
    }
    __syncthreads();
    const size_t ob = (((size_t)(n << 12)) + (y << 6)) << 6;   // *64
#pragma unroll
    for (int i = 0; i < 16; ++i) {
        const int idx = (i << 8) + tid;
        const int cl = idx & 63, xx = idx >> 6;
        dst[ob + ((size_t)xx << 6) + cl] = sm[cl][xx];
    }
}

// ---------------------------------------------------------------------------
// Deformable sampler -> NHWC bf16 output via LDS transpose.
// Source NCHW (fp32 x if SRC_F32, else bf16).  off bf16 flat (N,2C,H,W).
// block: 64 channels x 64 x at one (n,y).  grid (C/64, 64, 32).
// ---------------------------------------------------------------------------
template<int C, int SRC_F32>
__global__ __launch_bounds__(256) void deform_nhwc(
    const void* __restrict__ srcv, const unsigned short* __restrict__ off,
    unsigned short* __restrict__ outp)
{
    __shared__ unsigned short sm[64][66];
    const int cg = blockIdx.x, y = blockIdx.y, n = blockIdx.z;
    const int tid = threadIdx.x;
#pragma unroll
    for (int i = 0; i < 16; ++i) {
        const int idx = (i << 8) + tid;
        const int cl = idx >> 6, xx = idx & 63;
        const int c = (cg << 6) + cl;
        const int p = n * C + c;
        const size_t i0 = ((size_t)p << 12) + (y << 6) + xx;
        const unsigned int ob = *(const unsigned int*)(off + (i0 << 1));
        const float dy = bf2f((unsigned short)(ob & 0xffff));
        const float dx = bf2f((unsigned short)(ob >> 16));
        const float cy = fminf(fmaxf((float)y + dy, 0.f), 63.f);
        const float cx = fminf(fmaxf((float)xx + dx, 0.f), 63.f);
        const float y0f = floorf(cy), x0f = floorf(cx);
        const float fy = cy - y0f, fx = cx - x0f;
        const int yy0 = (int)y0f, xx0 = (int)x0f;
        const int yy1 = min(yy0 + 1, 63), xx1 = min(xx0 + 1, 63);
        float v00, v01, v10, v11;
        if constexpr (SRC_F32) {
            const float* qf = (const float*)srcv +
                ((size_t)((((n >> 3) * C + c) * 8 + (n & 7))) << 12);
            v00 = qf[(yy0 << 6) + xx0]; v01 = qf[(yy0 << 6) + xx1];
            v10 = qf[(yy1 << 6) + xx0]; v11 = qf[(yy1 << 6) + xx1];
        } else {
            const unsigned short* qh = (const unsigned short*)srcv + ((size_t)p << 12);
            v00 = bf2f(qh[(yy0 << 6) + xx0]); v01 = bf2f(qh[(yy0 << 6) + xx1]);
            v10 = bf2f(qh[(yy1 << 6) + xx0]); v11 = bf2f(qh[(yy1 << 6) + xx1]);
        }
        const float r = v00 * (1.f - fy) * (1.f - fx) + v01 * (1.f - fy) * fx +
                        v10 * fy * (1.f - fx) + v11 * fy * fx;
        sm[cl][xx] = f2bf(r);
    }
    __syncthreads();
    const size_t ob2 = (((size_t)(n << 12)) + (y << 6)) * C + (cg << 6);
#pragma unroll
    for (int i = 0; i < 16; ++i) {
        const int idx = (i << 8) + tid;
        const int cl = idx & 63, xx = idx >> 6;
        outp[ob2 + (size_t)xx * C + cl] = sm[cl][xx];
    }
}

// ---------------------------------------------------------------------------
extern "C" void kernel_launch(void* const* d_in, const int* in_sizes, int n_in,
                              void* d_out, int out_size, void* d_ws, size_t ws_size,
                              hipStream_t stream) {
    const float* x      = (const float*)d_in[0];
    const float* w_off1 = (const float*)d_in[3];
    const float* w1     = (const float*)d_in[4];
    const float* g1     = (const float*)d_in[5];
    const float* b1     = (const float*)d_in[6];
    const float* m1     = (const float*)d_in[7];
    const float* v1     = (const float*)d_in[8];
    const float* w_off2 = (const float*)d_in[9];
    const float* w2     = (const float*)d_in[10];
    const float* g2     = (const float*)d_in[11];
    const float* b2     = (const float*)d_in[12];
    const float* m2     = (const float*)d_in[13];
    const float* v2     = (const float*)d_in[14];
    float* out = (float*)d_out;

    char* ws = (char*)d_ws;
    const size_t MB = 1ull << 20;
    unsigned short* zp     = (unsigned short*)(ws);              // 4KB zeros
    unsigned short* wt1    = (unsigned short*)(ws + 1 * MB);
    unsigned short* wth1   = (unsigned short*)(ws + 4 * MB);
    unsigned short* wtoff2 = (unsigned short*)(ws + 5 * MB);
    unsigned short* wth2   = (unsigned short*)(ws + 6 * MB);
    unsigned short* xh     = (unsigned short*)(ws + 16 * MB);    // 64MB NHWC
    unsigned short* off1   = (unsigned short*)(ws + 80 * MB);    // 128MB
    unsigned short* samp1n = (unsigned short*)(ws + 208 * MB);   // 64MB, end 272MB
    unsigned short* h1     = (unsigned short*)(ws + 80 * MB);    // 16MB (off1 dead)
    unsigned short* h1n    = (unsigned short*)(ws + 96 * MB);    // 16MB
    unsigned short* off2   = (unsigned short*)(ws + 112 * MB);   // 32MB
    unsigned short* samp2n = (unsigned short*)(ws + 144 * MB);   // 16MB

    hipMemsetAsync(zp, 0, 4096, stream);
    xpose_in<<<dim3(64, 32), 256, 0, stream>>>(x, xh);
    wt_xpose<<<4608, 256, 0, stream>>>(w_off1, wt1,    256, 512, 1179648);
    wt_xpose<<<576,  256, 0, stream>>>(w1,     wth1,   256, 64,  147456);
    wt_xpose<<<288,  256, 0, stream>>>(w_off2, wtoff2, 64,  128, 73728);
    wt_xpose<<<144,  256, 0, stream>>>(w2,     wth2,   64,  64,  36864);

    // stage 1
    conv_mfma<256, 512, 512, false, 0><<<dim3(8, 256), 256, 0, stream>>>(
        xh, wt1, zp, nullptr, nullptr, nullptr, nullptr, off1);
    deform_nhwc<256, 1><<<dim3(4, 64, 32), 256, 0, stream>>>(x, off1, samp1n);
    conv_mfma<256, 64, 256, true, 0><<<dim3(1, 512), 256, 0, stream>>>(
        samp1n, wth1, zp, g1, b1, m1, v1, h1);

    // stage 2
    xpose64<<<dim3(64, 32), 256, 0, stream>>>(h1, h1n);
    conv_mfma<64, 128, 256, false, 0><<<dim3(2, 512), 256, 0, stream>>>(
        h1n, wtoff2, zp, nullptr, nullptr, nullptr, nullptr, off2);
    deform_nhwc<64, 0><<<dim3(1, 64, 32), 256, 0, stream>>>(h1, off2, samp2n);
    conv_mfma<64, 64, 256, true, 1><<<dim3(1, 512), 256, 0, stream>>>(
        samp2n, wth2, zp, g2, b2, m2, v2, out);
}